// Round 2
// baseline (79.293 us; speedup 1.0000x reference)
//
#include <hip/hip_runtime.h>

// Indexed segmented linear, bucketed-by-element grouped GEMM with bf16 MFMA.
//   segments (mi, mo, d): (96,96,1), (64,64,3), (32,32,5)
//   y[b, o*d+m] = sum_i x[b, i*d+m] * W[idx[b], i*mo+o]
//
// Pipeline (all on `stream`):
//   memset   : zero counts+cursor (512 B of ws)
//   hist     : per-block LDS histogram of widx -> counts[64]
//   scan     : offsets/tileoff prefix sums, block->element table blk2e
//   scatter  : rowids sorted by element (order within bucket irrelevant)
//   wprep    : W -> bf16, transposed per segment: Wt[e][seg][o][i], row stride mi+8
//   gemm     : per (element, 32-row tile): stage x slice (de-interleaved bf16,
//              padded rows) + Wt seg in LDS, 16x16x32 bf16 MFMA, store f32.
//
// LDS strides chosen so all ds_read_b128 fragment reads are 16B-aligned and
// <=2-way bank conflict (free): x rows d*mi+8 halves, W rows mi+8 halves.

#define BATCH     16384
#define IN_SIZE   448
#define OUT_SIZE  448
#define W_SIZE    14336
#define NELEM     64
#define RTILE     32          // rows per GEMM tile
#define MAXTILES  576         // >= sum_e ceil(cnt_e/32) worst case (512+63)
#define WT_ELEM   15872       // halves per element in Wt: 96*104 + 64*72 + 32*40

typedef __attribute__((ext_vector_type(8))) short short8;
typedef __attribute__((ext_vector_type(4))) float f32x4;

__device__ __forceinline__ unsigned short f2bf(float f) {
    unsigned int u = __float_as_uint(f);
    u += 0x7fffu + ((u >> 16) & 1u);        // round-to-nearest-even
    return (unsigned short)(u >> 16);
}

// ---------------- sort pipeline ----------------

__global__ void hist_kernel(const int* __restrict__ widx, int* __restrict__ counts) {
    __shared__ int h[NELEM];
    const int t = threadIdx.x;
    if (t < NELEM) h[t] = 0;
    __syncthreads();
    const int i = blockIdx.x * 256 + t;      // grid 64x256 == 16384 exactly
    atomicAdd(&h[widx[i]], 1);
    __syncthreads();
    if (t < NELEM && h[t]) atomicAdd(&counts[t], h[t]);
}

__global__ void scan_kernel(const int* __restrict__ counts, int* __restrict__ offsets,
                            int* __restrict__ tileoff, int* __restrict__ blk2e) {
    __shared__ int c[NELEM], off_s[NELEM + 1], tl_s[NELEM + 1];
    const int t = threadIdx.x;               // 64 threads
    c[t] = counts[t];
    for (int i = t; i < MAXTILES; i += 64) blk2e[i] = -1;
    __syncthreads();
    if (t == 0) {
        int o = 0, tl = 0;
        for (int e = 0; e < NELEM; ++e) {
            off_s[e] = o; tl_s[e] = tl;
            o += c[e]; tl += (c[e] + RTILE - 1) >> 5;
        }
        off_s[NELEM] = o; tl_s[NELEM] = tl;
    }
    __syncthreads();
    offsets[t] = off_s[t]; tileoff[t] = tl_s[t];
    if (t == 0) { offsets[NELEM] = off_s[NELEM]; tileoff[NELEM] = tl_s[NELEM]; }
    for (int b = tl_s[t]; b < tl_s[t + 1]; ++b) blk2e[b] = t;
}

__global__ void scatter_kernel(const int* __restrict__ widx, int* __restrict__ cursor,
                               const int* __restrict__ offsets, int* __restrict__ rowids) {
    const int i = blockIdx.x * 256 + threadIdx.x;   // 64x256 == 16384
    const int e = widx[i];
    const int pos = atomicAdd(&cursor[e], 1);
    rowids[offsets[e] + pos] = i;
}

// ---------------- weight preprocess: f32 -> bf16, transpose per segment ----------------

__global__ void wprep_kernel(const float* __restrict__ weights, unsigned short* __restrict__ wt) {
    const int e = blockIdx.x;
    const int t = threadIdx.x;
    const float* we = weights + e * W_SIZE;
    unsigned short* de = wt + e * WT_ELEM;
    for (int g = t; g < W_SIZE; g += 256) {
        int dst;
        if (g < 9216)       { int i = g / 96, o = g % 96;            dst = o * 104 + i; }
        else if (g < 13312) { int h = g - 9216; int i = h >> 6, o = h & 63;  dst = 9984  + o * 72 + i; }
        else                { int h = g - 13312; int i = h >> 5, o = h & 31; dst = 14592 + o * 40 + i; }
        de[dst] = f2bf(we[g]);
    }
}

// ---------------- grouped GEMM ----------------

template <int MI, int MO, int D, int XOFF, int YOFF, int WB>
__device__ __forceinline__ void do_seg(const float* __restrict__ x,
                                       const unsigned short* __restrict__ wt_e,
                                       const int* rid_s, int nrows,
                                       float* __restrict__ out,
                                       unsigned short* lds_x, unsigned short* lds_w,
                                       int t) {
    constexpr int XP    = MI * D + 8;        // x row stride (halves), pad keeps frags 2-way
    constexpr int WSTR  = MI + 8;            // W row stride (halves)
    constexpr int NT    = MO / 16;           // n-tiles
    constexpr int KB    = MI / 32;           // k-steps of 32
    constexpr int MTL   = 2 * D;             // m-tiles: 2 row-tiles x D channels
    constexpr int P     = (MI * D) / 32;     // float4 passes per 8-thread row group
    constexpr int WCH   = (MO * WSTR) / 8;   // 16B chunks of W segment

    // stage W segment (already bf16+transposed+padded in ws): plain 16B copies
    for (int idx = t; idx < WCH; idx += 256)
        *(uint4*)&lds_w[idx * 8] = *(const uint4*)&wt_e[WB + idx * 8];

    // stage x slice: de-interleave (i*d+m -> [m][i]) + convert to bf16
    {
        const int r = t >> 3, j = t & 7;     // 8 threads per row
        const float* xr = x + rid_s[r] * IN_SIZE + XOFF;
        #pragma unroll
        for (int p = 0; p < P; ++p) {
            const int c = (j + p * 8) * 4;
            const float4 v = *(const float4*)(xr + c);
            if (D == 1) {
                ushort4 w4 = { f2bf(v.x), f2bf(v.y), f2bf(v.z), f2bf(v.w) };
                *(ushort4*)&lds_x[r * XP + c] = w4;
            } else {
                const float vv[4] = { v.x, v.y, v.z, v.w };
                #pragma unroll
                for (int u = 0; u < 4; ++u) {
                    const int cc = c + u;
                    const int i = cc / D, mch = cc % D;
                    lds_x[r * XP + mch * MI + i] = f2bf(vv[u]);
                }
            }
        }
    }
    __syncthreads();

    // compute: C-tiles round-robin over 4 waves
    const int lane = t & 63, w = t >> 6;
    const int row_l = lane & 15, kg = lane >> 4;
    for (int ct = w; ct < MTL * NT; ct += 4) {
        const int mIdx = ct / NT, nt = ct - mIdx * NT;
        const int mt = mIdx & 1, mch = mIdx >> 1;
        f32x4 acc = {0.f, 0.f, 0.f, 0.f};
        #pragma unroll
        for (int kb = 0; kb < KB; ++kb) {
            // A: lane holds A[row=lane&15][k = (lane>>4)*8 .. +7]
            const short8 a = *(const short8*)&lds_x[(mt * 16 + row_l) * XP + mch * MI + kb * 32 + kg * 8];
            // B: lane holds B[k = (lane>>4)*8 .. +7][col=lane&15] from Wt[o][i]
            const short8 b = *(const short8*)&lds_w[(nt * 16 + row_l) * WSTR + kb * 32 + kg * 8];
            acc = __builtin_amdgcn_mfma_f32_16x16x32_bf16(a, b, acc, 0, 0, 0);
        }
        // D: col = lane&15, row = (lane>>4)*4 + reg
        const int o = nt * 16 + row_l;
        #pragma unroll
        for (int jj = 0; jj < 4; ++jj) {
            const int m = mt * 16 + kg * 4 + jj;
            if (m < nrows)
                out[rid_s[m] * OUT_SIZE + YOFF + o * D + mch] = acc[jj];
        }
    }
    __syncthreads();   // before next segment overwrites LDS
}

__global__ __launch_bounds__(256) void gemm_kernel(
    const float* __restrict__ x, const unsigned short* __restrict__ wt,
    const int* __restrict__ rowids, const int* __restrict__ offsets,
    const int* __restrict__ tileoff, const int* __restrict__ blk2e,
    float* __restrict__ out) {
    __shared__ __align__(16) unsigned short lds_x[RTILE * 200];  // max seg1: 32*200
    __shared__ __align__(16) unsigned short lds_w[9984];         // max seg0: 96*104
    __shared__ int rid_s[RTILE];

    const int t = threadIdx.x;
    const int e = blk2e[blockIdx.x];
    if (e < 0) return;
    const int tile  = blockIdx.x - tileoff[e];
    const int r0    = offsets[e];
    const int cnt   = offsets[e + 1] - r0;
    const int rbase = r0 + tile * RTILE;
    const int nrows = min(RTILE, cnt - tile * RTILE);
    if (t < RTILE) rid_s[t] = rowids[rbase + min(t, nrows - 1)];  // clamp: ghosts stage real data
    __syncthreads();

    const unsigned short* wt_e = wt + e * WT_ELEM;
    do_seg<96, 96, 1,   0,   0,     0>(x, wt_e, rid_s, nrows, out, lds_x, lds_w, t);
    do_seg<64, 64, 3,  96,  96,  9984>(x, wt_e, rid_s, nrows, out, lds_x, lds_w, t);
    do_seg<32, 32, 5, 288, 288, 14592>(x, wt_e, rid_s, nrows, out, lds_x, lds_w, t);
}

// ---------------- launcher ----------------

extern "C" void kernel_launch(void* const* d_in, const int* in_sizes, int n_in,
                              void* d_out, int out_size, void* d_ws, size_t ws_size,
                              hipStream_t stream) {
    const float* weights = (const float*)d_in[0];   // [64, 14336] f32
    const float* x       = (const float*)d_in[1];   // [16384, 448] f32
    const int*   widx    = (const int*)d_in[2];     // [16384] int32
    float*       out     = (float*)d_out;           // [16384, 448] f32

    char* ws = (char*)d_ws;
    int* counts  = (int*)(ws + 0);                  // 64
    int* cursor  = (int*)(ws + 256);                // 64
    int* offsets = (int*)(ws + 512);                // 65
    int* tileoff = (int*)(ws + 1024);               // 65
    int* blk2e   = (int*)(ws + 2048);               // 576
    int* rowids  = (int*)(ws + 8192);               // 16384
    unsigned short* wt = (unsigned short*)(ws + 8192 + 65536);  // 64*15872 halves = 2.03 MB

    hipMemsetAsync(ws, 0, 512, stream);             // counts + cursor
    hist_kernel   <<<64, 256, 0, stream>>>(widx, counts);
    scan_kernel   <<<1,   64, 0, stream>>>(counts, offsets, tileoff, blk2e);
    scatter_kernel<<<64, 256, 0, stream>>>(widx, cursor, offsets, rowids);
    wprep_kernel  <<<64, 256, 0, stream>>>(weights, wt);
    gemm_kernel   <<<MAXTILES, 256, 0, stream>>>(x, wt, rowids, offsets, tileoff, blk2e, out);
}

// Round 3
// 72.954 us; speedup vs baseline: 1.0869x; 1.0869x over previous
//
#include <hip/hip_runtime.h>

// Indexed segmented linear, bucketed-by-element grouped GEMM with bf16 MFMA.
//   segments (mi, mo, d): (96,96,1), (64,64,3), (32,32,5)
//   y[b, o*d+m] = sum_i x[b, i*d+m] * W[idx[b], i*mo+o]
//
// Pipeline (all on `stream`, NO memset — nothing relies on zeroed ws):
//   K1 combo (128 blocks): blk 0-63  -> per-block histogram of widx (full overwrite)
//                          blk 64-127-> wprep: W -> bf16 transposed Wt[e][seg][o][i]
//   K2 scan  (1 block)   : counts = sum per-block hists; offsets/tileoff prefix
//                          sums; blk2e table; zero cursor
//   K3 scatter (64 blks) : rowids bucketed by element (atomic cursor)
//   K4 gemm (576 blks)   : per (element, 32-row tile): stage x (de-interleaved
//                          bf16, padded rows) + Wt seg in LDS, 16x16x32 bf16
//                          MFMA, store f32. Unchanged from the passing R2 core.

#define BATCH     16384
#define IN_SIZE   448
#define OUT_SIZE  448
#define W_SIZE    14336
#define NELEM     64
#define RTILE     32          // rows per GEMM tile
#define MAXTILES  576         // >= sum_e ceil(cnt_e/32) worst case (512+63)
#define WT_ELEM   15872       // halves per element in Wt: 96*104 + 64*72 + 32*40

typedef __attribute__((ext_vector_type(8))) short short8;
typedef __attribute__((ext_vector_type(4))) float f32x4;

__device__ __forceinline__ unsigned short f2bf(float f) {
    unsigned int u = __float_as_uint(f);
    u += 0x7fffu + ((u >> 16) & 1u);        // round-to-nearest-even
    return (unsigned short)(u >> 16);
}

// ---------------- K1: per-block hist (blocks 0..63) + wprep (blocks 64..127) ----

__global__ __launch_bounds__(256) void combo_kernel(
    const int* __restrict__ widx, const float* __restrict__ weights,
    int* __restrict__ hists, unsigned short* __restrict__ wt) {
    const int t = threadIdx.x;
    if (blockIdx.x < 64) {
        // per-block histogram: every slot overwritten -> no pre-zero of ws needed
        __shared__ int h[NELEM];
        if (t < NELEM) h[t] = 0;
        __syncthreads();
        atomicAdd(&h[widx[blockIdx.x * 256 + t]], 1);
        __syncthreads();
        if (t < NELEM) hists[blockIdx.x * NELEM + t] = h[t];
    } else {
        // wprep: destination-major (coalesced ushort writes), scattered L2 reads
        const int e = blockIdx.x - 64;
        const float* __restrict__ we = weights + e * W_SIZE;
        unsigned short* __restrict__ de = wt + e * WT_ELEM;
        for (int dst = t; dst < WT_ELEM; dst += 256) {
            float v;
            if (dst < 9984) {
                const int o = dst / 104, i = dst - o * 104;
                v = (i < 96) ? we[i * 96 + o] : 0.0f;
            } else if (dst < 14592) {
                const int h2 = dst - 9984; const int o = h2 / 72, i = h2 - o * 72;
                v = (i < 64) ? we[9216 + i * 64 + o] : 0.0f;
            } else {
                const int h2 = dst - 14592; const int o = h2 / 40, i = h2 - o * 40;
                v = (i < 32) ? we[13312 + i * 32 + o] : 0.0f;
            }
            de[dst] = f2bf(v);
        }
    }
}

// ---------------- K2: scan ----------------

__global__ void scan_kernel(const int* __restrict__ hists, int* __restrict__ offsets,
                            int* __restrict__ tileoff, int* __restrict__ blk2e,
                            int* __restrict__ cursor) {
    __shared__ int c[NELEM], off_s[NELEM + 1], tl_s[NELEM + 1];
    const int t = threadIdx.x;               // 64 threads
    int s = 0;
    for (int b = 0; b < 64; ++b) s += hists[b * NELEM + t];
    c[t] = s;
    cursor[t] = 0;
    for (int i = t; i < MAXTILES; i += 64) blk2e[i] = -1;
    __syncthreads();
    if (t == 0) {
        int o = 0, tl = 0;
        for (int e = 0; e < NELEM; ++e) {
            off_s[e] = o; tl_s[e] = tl;
            o += c[e]; tl += (c[e] + RTILE - 1) >> 5;
        }
        off_s[NELEM] = o; tl_s[NELEM] = tl;
    }
    __syncthreads();
    offsets[t] = off_s[t]; tileoff[t] = tl_s[t];
    if (t == 0) { offsets[NELEM] = off_s[NELEM]; tileoff[NELEM] = tl_s[NELEM]; }
    for (int b = tl_s[t]; b < tl_s[t + 1]; ++b) blk2e[b] = t;
}

// ---------------- K3: scatter ----------------

__global__ __launch_bounds__(256) void scatter_kernel(
    const int* __restrict__ widx, int* __restrict__ cursor,
    const int* __restrict__ offsets, int* __restrict__ rowids) {
    const int i = blockIdx.x * 256 + threadIdx.x;   // 64x256 == 16384
    const int e = widx[i];
    const int pos = atomicAdd(&cursor[e], 1);
    rowids[offsets[e] + pos] = i;
}

// ---------------- K4: grouped GEMM ----------------

template <int MI, int MO, int D, int XOFF, int YOFF, int WB>
__device__ __forceinline__ void do_seg(const float* __restrict__ x,
                                       const unsigned short* __restrict__ wt_e,
                                       const int* rid_s, int nrows,
                                       float* __restrict__ out,
                                       unsigned short* lds_x, unsigned short* lds_w,
                                       int t) {
    constexpr int XP    = MI * D + 8;        // x row stride (halves)
    constexpr int WSTR  = MI + 8;            // W row stride (halves)
    constexpr int NT    = MO / 16;           // n-tiles
    constexpr int KB    = MI / 32;           // k-steps of 32
    constexpr int MTL   = 2 * D;             // m-tiles: 2 row-tiles x D channels
    constexpr int P     = (MI * D) / 32;     // float4 passes per 8-thread row group
    constexpr int WCH   = (MO * WSTR) / 8;   // 16B chunks of W segment

    // stage W segment (already bf16+transposed+padded in ws): plain 16B copies
    for (int idx = t; idx < WCH; idx += 256)
        *(uint4*)&lds_w[idx * 8] = *(const uint4*)&wt_e[WB + idx * 8];

    // stage x slice: de-interleave (i*d+m -> [m][i]) + convert to bf16
    {
        const int r = t >> 3, j = t & 7;     // 8 threads per row
        const float* xr = x + rid_s[r] * IN_SIZE + XOFF;
        #pragma unroll
        for (int p = 0; p < P; ++p) {
            const int c = (j + p * 8) * 4;
            const float4 v = *(const float4*)(xr + c);
            if (D == 1) {
                ushort4 w4 = { f2bf(v.x), f2bf(v.y), f2bf(v.z), f2bf(v.w) };
                *(ushort4*)&lds_x[r * XP + c] = w4;
            } else {
                const float vv[4] = { v.x, v.y, v.z, v.w };
                #pragma unroll
                for (int u = 0; u < 4; ++u) {
                    const int cc = c + u;
                    const int i = cc / D, mch = cc % D;
                    lds_x[r * XP + mch * MI + i] = f2bf(vv[u]);
                }
            }
        }
    }
    __syncthreads();

    // compute: C-tiles round-robin over 4 waves
    const int lane = t & 63, w = t >> 6;
    const int row_l = lane & 15, kg = lane >> 4;
    for (int ct = w; ct < MTL * NT; ct += 4) {
        const int mIdx = ct / NT, nt = ct - mIdx * NT;
        const int mt = mIdx & 1, mch = mIdx >> 1;
        f32x4 acc = {0.f, 0.f, 0.f, 0.f};
        #pragma unroll
        for (int kb = 0; kb < KB; ++kb) {
            // A: lane holds A[row=lane&15][k = (lane>>4)*8 .. +7]
            const short8 a = *(const short8*)&lds_x[(mt * 16 + row_l) * XP + mch * MI + kb * 32 + kg * 8];
            // B: lane holds B[k = (lane>>4)*8 .. +7][col=lane&15] from Wt[o][i]
            const short8 b = *(const short8*)&lds_w[(nt * 16 + row_l) * WSTR + kb * 32 + kg * 8];
            acc = __builtin_amdgcn_mfma_f32_16x16x32_bf16(a, b, acc, 0, 0, 0);
        }
        // D: col = lane&15, row = (lane>>4)*4 + reg
        const int o = nt * 16 + row_l;
        #pragma unroll
        for (int jj = 0; jj < 4; ++jj) {
            const int m = mt * 16 + kg * 4 + jj;
            if (m < nrows)
                out[rid_s[m] * OUT_SIZE + YOFF + o * D + mch] = acc[jj];
        }
    }
    __syncthreads();   // before next segment overwrites LDS
}

__global__ __launch_bounds__(256) void gemm_kernel(
    const float* __restrict__ x, const unsigned short* __restrict__ wt,
    const int* __restrict__ rowids, const int* __restrict__ offsets,
    const int* __restrict__ tileoff, const int* __restrict__ blk2e,
    float* __restrict__ out) {
    __shared__ __align__(16) unsigned short lds_x[RTILE * 200];  // max seg1: 32*200
    __shared__ __align__(16) unsigned short lds_w[9984];         // max seg0: 96*104
    __shared__ int rid_s[RTILE];

    const int t = threadIdx.x;
    const int e = blk2e[blockIdx.x];
    if (e < 0) return;
    const int tile  = blockIdx.x - tileoff[e];
    const int r0    = offsets[e];
    const int cnt   = offsets[e + 1] - r0;
    const int rbase = r0 + tile * RTILE;
    const int nrows = min(RTILE, cnt - tile * RTILE);
    if (t < RTILE) rid_s[t] = rowids[rbase + min(t, nrows - 1)];  // clamp: ghosts stage real data
    __syncthreads();

    const unsigned short* wt_e = wt + e * WT_ELEM;
    do_seg<96, 96, 1,   0,   0,     0>(x, wt_e, rid_s, nrows, out, lds_x, lds_w, t);
    do_seg<64, 64, 3,  96,  96,  9984>(x, wt_e, rid_s, nrows, out, lds_x, lds_w, t);
    do_seg<32, 32, 5, 288, 288, 14592>(x, wt_e, rid_s, nrows, out, lds_x, lds_w, t);
}

// ---------------- launcher ----------------

extern "C" void kernel_launch(void* const* d_in, const int* in_sizes, int n_in,
                              void* d_out, int out_size, void* d_ws, size_t ws_size,
                              hipStream_t stream) {
    const float* weights = (const float*)d_in[0];   // [64, 14336] f32
    const float* x       = (const float*)d_in[1];   // [16384, 448] f32
    const int*   widx    = (const int*)d_in[2];     // [16384] int32
    float*       out     = (float*)d_out;           // [16384, 448] f32

    char* ws = (char*)d_ws;
    int* hists   = (int*)(ws + 0);                  // 64*64 ints = 16 KB (fully overwritten)
    int* cursor  = (int*)(ws + 16384);              // 64 (zeroed by scan)
    int* offsets = (int*)(ws + 16640);              // 65
    int* tileoff = (int*)(ws + 17152);              // 65
    int* blk2e   = (int*)(ws + 17664);              // 576 (fully overwritten by scan)
    int* rowids  = (int*)(ws + 24576);              // 16384 (fully overwritten)
    unsigned short* wt = (unsigned short*)(ws + 24576 + 65536);  // 64*15872 halves

    combo_kernel  <<<128, 256, 0, stream>>>(widx, weights, hists, wt);
    scan_kernel   <<<1,    64, 0, stream>>>(hists, offsets, tileoff, blk2e, cursor);
    scatter_kernel<<<64,  256, 0, stream>>>(widx, cursor, offsets, rowids);
    gemm_kernel   <<<MAXTILES, 256, 0, stream>>>(x, wt, rowids, offsets, tileoff, blk2e, out);
}

// Round 4
// 66.719 us; speedup vs baseline: 1.1885x; 1.0935x over previous
//
#include <hip/hip_runtime.h>

// Indexed segmented linear, bucketed-by-element grouped GEMM with bf16 MFMA.
//   segments (mi, mo, d): (96,96,1), (64,64,3), (32,32,5)
//   y[b, o*d+m] = sum_i x[b, i*d+m] * W[idx[b], i*mo+o]
//
// Pipeline (all on `stream`, NO memset):
//   K1 combo (128 blocks): blk 0-63  -> per-block histogram of widx
//                          blk 64-127-> wprep via LDS-tiled transpose:
//                                       W -> bf16 Wt[e][seg][o][i] (padded rows)
//   K2 scan  (1 block)   : counts; offsets/tileoff prefix sums; blk2e; cursor=0
//   K3 scatter (64 blks) : rowids bucketed by element (atomic cursor)
//   K4 gemm (3*576 blks) : one block = one (segment, 32-row tile) -> stage x
//                          (de-interleaved bf16) + Wt seg in LDS, 16x16x32 bf16
//                          MFMA, store f32. Segment-parallel for occupancy.

#define BATCH     16384
#define IN_SIZE   448
#define OUT_SIZE  448
#define W_SIZE    14336
#define NELEM     64
#define RTILE     32          // rows per GEMM tile
#define MAXTILES  576         // >= sum_e ceil(cnt_e/32) worst case (512+63)
#define WT_ELEM   15872       // halves per element in Wt: 96*104 + 64*72 + 32*40

typedef __attribute__((ext_vector_type(8))) short short8;
typedef __attribute__((ext_vector_type(4))) float f32x4;

__device__ __forceinline__ unsigned short f2bf(float f) {
    unsigned int u = __float_as_uint(f);
    u += 0x7fffu + ((u >> 16) & 1u);        // round-to-nearest-even
    return (unsigned short)(u >> 16);
}

// ---------------- K1: per-block hist (blocks 0..63) + wprep (blocks 64..127) ----

__device__ __forceinline__ void wprep_seg(const float* __restrict__ we,
                                          unsigned short* __restrict__ de,
                                          unsigned short* lw, int t,
                                          int SRC, int CNT, int MO, int STR,
                                          int DB, int LWS, int MI) {
    // load segment (coalesced), bf16-convert, into padded LDS [i][o] stride LWS
    for (int g = t; g < CNT; g += 256) {
        const int i = g / MO, o = g - i * MO;
        lw[i * LWS + o] = f2bf(we[SRC + g]);
    }
    __syncthreads();
    // write transposed (coalesced): de[DB + o*STR + i] = lw[i*LWS + o]
    const int TOT = MO * STR;
    for (int d = t; d < TOT; d += 256) {
        const int o = d / STR, i = d - o * STR;
        de[DB + d] = (i < MI) ? lw[i * LWS + o] : (unsigned short)0;
    }
    __syncthreads();
}

__global__ __launch_bounds__(256) void combo_kernel(
    const int* __restrict__ widx, const float* __restrict__ weights,
    int* __restrict__ hists, unsigned short* __restrict__ wt) {
    const int t = threadIdx.x;
    if (blockIdx.x < 64) {
        __shared__ int h[NELEM];
        if (t < NELEM) h[t] = 0;
        __syncthreads();
        atomicAdd(&h[widx[blockIdx.x * 256 + t]], 1);
        __syncthreads();
        if (t < NELEM) hists[blockIdx.x * NELEM + t] = h[t];
    } else {
        __shared__ unsigned short lw[9408];           // 96 * 98 (padded stride)
        const int e = blockIdx.x - 64;
        const float* __restrict__ we = weights + e * W_SIZE;
        unsigned short* __restrict__ de = wt + e * WT_ELEM;
        wprep_seg(we, de, lw, t,     0, 9216, 96, 104,     0, 98, 96);
        wprep_seg(we, de, lw, t,  9216, 4096, 64,  72,  9984, 66, 64);
        wprep_seg(we, de, lw, t, 13312, 1024, 32,  40, 14592, 34, 32);
    }
}

// ---------------- K2: scan ----------------

__global__ void scan_kernel(const int* __restrict__ hists, int* __restrict__ offsets,
                            int* __restrict__ tileoff, int* __restrict__ blk2e,
                            int* __restrict__ cursor) {
    __shared__ int c[NELEM], off_s[NELEM + 1], tl_s[NELEM + 1];
    const int t = threadIdx.x;               // 64 threads
    int s = 0;
    for (int b = 0; b < 64; ++b) s += hists[b * NELEM + t];
    c[t] = s;
    cursor[t] = 0;
    for (int i = t; i < MAXTILES; i += 64) blk2e[i] = -1;
    __syncthreads();
    if (t == 0) {
        int o = 0, tl = 0;
        for (int e = 0; e < NELEM; ++e) {
            off_s[e] = o; tl_s[e] = tl;
            o += c[e]; tl += (c[e] + RTILE - 1) >> 5;
        }
        off_s[NELEM] = o; tl_s[NELEM] = tl;
    }
    __syncthreads();
    offsets[t] = off_s[t]; tileoff[t] = tl_s[t];
    if (t == 0) { offsets[NELEM] = off_s[NELEM]; tileoff[NELEM] = tl_s[NELEM]; }
    for (int b = tl_s[t]; b < tl_s[t + 1]; ++b) blk2e[b] = t;
}

// ---------------- K3: scatter ----------------

__global__ __launch_bounds__(256) void scatter_kernel(
    const int* __restrict__ widx, int* __restrict__ cursor,
    const int* __restrict__ offsets, int* __restrict__ rowids) {
    const int i = blockIdx.x * 256 + threadIdx.x;   // 64x256 == 16384
    const int e = widx[i];
    const int pos = atomicAdd(&cursor[e], 1);
    rowids[offsets[e] + pos] = i;
}

// ---------------- K4: grouped GEMM, one block = (segment, tile) ----------------

template <int MI, int MO, int D, int XOFF, int YOFF, int WB>
__device__ __forceinline__ void do_seg(const float* __restrict__ x,
                                       const unsigned short* __restrict__ wt_e,
                                       const int* rid_s, int nrows,
                                       float* __restrict__ out,
                                       unsigned short* lds_w, unsigned short* lds_x,
                                       int t) {
    constexpr int XP    = MI * D + 8;        // x row stride (halves)
    constexpr int WSTR  = MI + 8;            // W row stride (halves)
    constexpr int NT    = MO / 16;           // n-tiles
    constexpr int KB    = MI / 32;           // k-steps of 32
    constexpr int MTL   = 2 * D;             // m-tiles: 2 row-tiles x D channels
    constexpr int P     = (MI * D) / 32;     // float4 passes per 8-thread row group
    constexpr int WCH   = (MO * WSTR) / 8;   // 16B chunks of W segment

    // stage W segment (already bf16+transposed+padded in ws): 16B copies
    for (int idx = t; idx < WCH; idx += 256)
        *(uint4*)&lds_w[idx * 8] = *(const uint4*)&wt_e[WB + idx * 8];

    // stage x slice: de-interleave (i*d+m -> [m][i]) + convert to bf16
    {
        const int r = t >> 3, j = t & 7;     // 8 threads per row
        const float* xr = x + rid_s[r] * IN_SIZE + XOFF;
        #pragma unroll
        for (int p = 0; p < P; ++p) {
            const int c = (j + p * 8) * 4;
            const float4 v = *(const float4*)(xr + c);
            if (D == 1) {
                ushort4 w4 = { f2bf(v.x), f2bf(v.y), f2bf(v.z), f2bf(v.w) };
                *(ushort4*)&lds_x[r * XP + c] = w4;
            } else {
                const float vv[4] = { v.x, v.y, v.z, v.w };
                #pragma unroll
                for (int u = 0; u < 4; ++u) {
                    const int cc = c + u;
                    const int i = cc / D, mch = cc % D;
                    lds_x[r * XP + mch * MI + i] = f2bf(vv[u]);
                }
            }
        }
    }
    __syncthreads();

    // compute: C-tiles round-robin over 4 waves
    const int lane = t & 63, w = t >> 6;
    const int row_l = lane & 15, kg = lane >> 4;
    for (int ct = w; ct < MTL * NT; ct += 4) {
        const int mIdx = ct / NT, nt = ct - mIdx * NT;
        const int mt = mIdx & 1, mch = mIdx >> 1;
        f32x4 acc = {0.f, 0.f, 0.f, 0.f};
        #pragma unroll
        for (int kb = 0; kb < KB; ++kb) {
            // A: lane holds A[row=lane&15][k = (lane>>4)*8 .. +7]
            const short8 a = *(const short8*)&lds_x[(mt * 16 + row_l) * XP + mch * MI + kb * 32 + kg * 8];
            // B: lane holds B[k = (lane>>4)*8 .. +7][col=lane&15] from Wt[o][i]
            const short8 b = *(const short8*)&lds_w[(nt * 16 + row_l) * WSTR + kb * 32 + kg * 8];
            acc = __builtin_amdgcn_mfma_f32_16x16x32_bf16(a, b, acc, 0, 0, 0);
        }
        // D: col = lane&15, row = (lane>>4)*4 + reg
        const int o = nt * 16 + row_l;
        #pragma unroll
        for (int jj = 0; jj < 4; ++jj) {
            const int m = mt * 16 + kg * 4 + jj;
            if (m < nrows)
                out[rid_s[m] * OUT_SIZE + YOFF + o * D + mch] = acc[jj];
        }
    }
}

__global__ __launch_bounds__(256) void gemm_kernel(
    const float* __restrict__ x, const unsigned short* __restrict__ wt,
    const int* __restrict__ rowids, const int* __restrict__ offsets,
    const int* __restrict__ tileoff, const int* __restrict__ blk2e,
    float* __restrict__ out) {
    // union LDS: max over segs of (W halves + x halves):
    //   seg0: 96*104 + 32*104 = 13312 ; seg1: 64*72 + 32*200 = 11008 ; seg2: 1280+5376
    __shared__ __align__(16) unsigned short lds[13312];
    __shared__ int rid_s[RTILE];

    const int t   = threadIdx.x;
    const int seg = blockIdx.x / MAXTILES;
    const int tb  = blockIdx.x - seg * MAXTILES;
    const int e   = blk2e[tb];
    if (e < 0) return;
    const int tile  = tb - tileoff[e];
    const int r0    = offsets[e];
    const int cnt   = offsets[e + 1] - r0;
    const int rbase = r0 + tile * RTILE;
    const int nrows = min(RTILE, cnt - tile * RTILE);
    if (t < RTILE) rid_s[t] = rowids[rbase + min(t, nrows - 1)];  // clamp: ghosts stage real data
    __syncthreads();

    const unsigned short* wt_e = wt + e * WT_ELEM;
    if (seg == 0)
        do_seg<96, 96, 1,   0,   0,     0>(x, wt_e, rid_s, nrows, out, lds, lds + 9984, t);
    else if (seg == 1)
        do_seg<64, 64, 3,  96,  96,  9984>(x, wt_e, rid_s, nrows, out, lds, lds + 4608, t);
    else
        do_seg<32, 32, 5, 288, 288, 14592>(x, wt_e, rid_s, nrows, out, lds, lds + 1280, t);
}

// ---------------- launcher ----------------

extern "C" void kernel_launch(void* const* d_in, const int* in_sizes, int n_in,
                              void* d_out, int out_size, void* d_ws, size_t ws_size,
                              hipStream_t stream) {
    const float* weights = (const float*)d_in[0];   // [64, 14336] f32
    const float* x       = (const float*)d_in[1];   // [16384, 448] f32
    const int*   widx    = (const int*)d_in[2];     // [16384] int32
    float*       out     = (float*)d_out;           // [16384, 448] f32

    char* ws = (char*)d_ws;
    int* hists   = (int*)(ws + 0);                  // 64*64 ints = 16 KB (fully overwritten)
    int* cursor  = (int*)(ws + 16384);              // 64 (zeroed by scan)
    int* offsets = (int*)(ws + 16640);              // 65
    int* tileoff = (int*)(ws + 17152);              // 65
    int* blk2e   = (int*)(ws + 17664);              // 576 (fully overwritten by scan)
    int* rowids  = (int*)(ws + 24576);              // 16384 (fully overwritten)
    unsigned short* wt = (unsigned short*)(ws + 24576 + 65536);  // 64*15872 halves

    combo_kernel  <<<128, 256, 0, stream>>>(widx, weights, hists, wt);
    scan_kernel   <<<1,    64, 0, stream>>>(hists, offsets, tileoff, blk2e, cursor);
    scatter_kernel<<<64,  256, 0, stream>>>(widx, cursor, offsets, rowids);
    gemm_kernel   <<<3 * MAXTILES, 256, 0, stream>>>(x, wt, rowids, offsets, tileoff, blk2e, out);
}

// Round 5
// 59.792 us; speedup vs baseline: 1.3261x; 1.1158x over previous
//
#include <hip/hip_runtime.h>

// Indexed segmented linear, bucketed-by-element grouped GEMM with bf16 MFMA.
//   segments (mi, mo, d): (96,96,1), (64,64,3), (32,32,5)
//   y[b, o*d+m] = sum_i x[b, i*d+m] * W[idx[b], i*mo+o]
//
// Pipeline (3 kernels, no memset):
//   K1 hist (128 blk x 128): per-128-row-chunk histogram of widx
//   K2 scatterx (192 blk x 1024):
//        blk 0-127 : derive per-block bucket bases from hists (fused scan);
//                    scatter rows -> rowids; convert+de-interleave x rows into
//                    bucketed bf16 arrays xs0/xs1/xs2 (row strides 104/200/168
//                    halves = exact LDS tile image). Block 0 writes
//                    offsets/tileoff/blk2e for K3.
//        blk 128-191: wprep: W -> bf16 transposed Wt[e][seg][o][i] (padded)
//   K3 gemm (3*576 blk x 256): one block = (segment, 32-row tile).
//        Stage W seg + x tile as PURE LINEAR uint4 copies (both pre-formatted
//        in ws), 16x16x32 bf16 MFMA, store f32 via rowids.

#define BATCH     16384
#define IN_SIZE   448
#define OUT_SIZE  448
#define W_SIZE    14336
#define NELEM     64
#define RTILE     32
#define MAXTILES  576         // >= 512 + 63 worst case
#define WT_ELEM   15872       // halves: 96*104 + 64*72 + 32*40

#define XP0 104               // xs row strides in halves (MI*D + 8)
#define XP1 200
#define XP2 168

typedef __attribute__((ext_vector_type(8))) short short8;
typedef __attribute__((ext_vector_type(4))) float f32x4;

__device__ __forceinline__ unsigned short f2bf(float f) {
    unsigned int u = __float_as_uint(f);
    u += 0x7fffu + ((u >> 16) & 1u);        // round-to-nearest-even
    return (unsigned short)(u >> 16);
}

// ---------------- K1: per-chunk histogram ----------------

__global__ __launch_bounds__(128) void hist_kernel(const int* __restrict__ widx,
                                                   int* __restrict__ hists) {
    __shared__ int h[NELEM];
    const int t = threadIdx.x;
    if (t < NELEM) h[t] = 0;
    __syncthreads();
    atomicAdd(&h[widx[blockIdx.x * 128 + t]], 1);
    __syncthreads();
    if (t < NELEM) hists[blockIdx.x * NELEM + t] = h[t];
}

// ---------------- K2: fused scan + scatter + x-reformat, plus wprep ----------------

__device__ __forceinline__ void wprep_seg(const float* __restrict__ we,
                                          unsigned short* __restrict__ de,
                                          unsigned short* lw, int t,
                                          int SRC, int CNT, int MO, int STR,
                                          int DB, int LWS, int MI) {
    for (int g = t; g < CNT; g += 1024) {
        const int i = g / MO, o = g - i * MO;
        lw[i * LWS + o] = f2bf(we[SRC + g]);
    }
    __syncthreads();
    const int TOT = MO * STR;
    for (int d = t; d < TOT; d += 1024) {
        const int o = d / STR, i = d - o * STR;
        de[DB + d] = (i < MI) ? lw[i * LWS + o] : (unsigned short)0;
    }
    __syncthreads();
}

__global__ __launch_bounds__(1024) void scatterx_kernel(
    const int* __restrict__ widx, const float* __restrict__ x,
    const float* __restrict__ weights, const int* __restrict__ hists,
    int* __restrict__ offsets, int* __restrict__ tileoff, int* __restrict__ blk2e,
    int* __restrict__ rowids, unsigned short* __restrict__ wt,
    unsigned short* __restrict__ xs0, unsigned short* __restrict__ xs1,
    unsigned short* __restrict__ xs2) {
    const int t = threadIdx.x;

    if (blockIdx.x >= 128) {                 // ---- wprep role ----
        __shared__ unsigned short lw[9408];  // 96 * 98 padded
        const int e = blockIdx.x - 128;
        const float* __restrict__ we = weights + e * W_SIZE;
        unsigned short* __restrict__ de = wt + e * WT_ELEM;
        wprep_seg(we, de, lw, t,     0, 9216, 96, 104,     0, 98, 96);
        wprep_seg(we, de, lw, t,  9216, 4096, 64,  72,  9984, 66, 64);
        wprep_seg(we, de, lw, t, 13312, 1024, 32,  40, 14592, 34, 32);
        return;
    }

    // ---- scatter role: 128 rows per block ----
    __shared__ int tot_s[NELEM], pre_s[NELEM], base_s[NELEM];
    __shared__ int off_s[NELEM + 1], tl_s[NELEM + 1];
    __shared__ int rowpos[128];
    const int b = blockIdx.x;

    if (t < NELEM) {
        int before = 0, tot = 0;
        for (int bb = 0; bb < 128; ++bb) {
            const int h = hists[bb * NELEM + t];
            before += (bb < b) ? h : 0;
            tot += h;
        }
        tot_s[t] = tot; pre_s[t] = before;
    }
    __syncthreads();
    if (t == 0) {
        int o = 0, tl = 0;
        for (int e = 0; e < NELEM; ++e) {
            off_s[e] = o; tl_s[e] = tl;
            o += tot_s[e]; tl += (tot_s[e] + RTILE - 1) >> 5;
        }
        off_s[NELEM] = o; tl_s[NELEM] = tl;
    }
    __syncthreads();
    if (t < NELEM) base_s[t] = off_s[t] + pre_s[t];

    if (b == 0) {                            // write tables for K3
        if (t < NELEM) { offsets[t] = off_s[t]; tileoff[t] = tl_s[t]; }
        if (t == 0)    { offsets[NELEM] = off_s[NELEM]; tileoff[NELEM] = tl_s[NELEM]; }
        for (int i = t; i < MAXTILES; i += 1024) blk2e[i] = -1;
        __syncthreads();
        if (t < NELEM)
            for (int bb = tl_s[t]; bb < tl_s[t + 1]; ++bb) blk2e[bb] = t;
    }
    __syncthreads();

    const int r = t >> 3, j = t & 7;         // 128 rows, 8 threads/row
    const int row = b * 128 + r;
    const int e = widx[row];
    if (j == 0) {
        const int pos = atomicAdd(&base_s[e], 1);
        rowpos[r] = pos;
        rowids[pos] = row;
    }
    __syncthreads();
    const int pos = rowpos[r];

    const float* __restrict__ xr = x + (size_t)row * IN_SIZE;
    unsigned short* __restrict__ d0 = xs0 + (size_t)pos * XP0;
    unsigned short* __restrict__ d1 = xs1 + (size_t)pos * XP1;
    unsigned short* __restrict__ d2 = xs2 + (size_t)pos * XP2;
    #pragma unroll
    for (int k = 0; k < 14; ++k) {
        const float4 v = ((const float4*)xr)[j + k * 8];
        const float vv[4] = { v.x, v.y, v.z, v.w };
        #pragma unroll
        for (int u = 0; u < 4; ++u) {
            const int c = (j + k * 8) * 4 + u;
            const unsigned short bf = f2bf(vv[u]);
            if (c < 96) d0[c] = bf;
            else if (c < 288) { const int h = c - 96;  const int i = h / 3, m = h - 3 * i; d1[m * 64 + i] = bf; }
            else              { const int h = c - 288; const int i = h / 5, m = h - 5 * i; d2[m * 32 + i] = bf; }
        }
    }
}

// ---------------- K3: grouped GEMM, one block = (segment, tile) ----------------

template <int MI, int MO, int D, int YOFF, int WB>
__device__ __forceinline__ void do_seg(const unsigned short* __restrict__ xs_seg,
                                       const unsigned short* __restrict__ wt_e,
                                       int rbase, const int* rid_s, int nrows,
                                       float* __restrict__ out,
                                       unsigned short* lds_w, unsigned short* lds_x,
                                       int t) {
    constexpr int XP   = MI * D + 8;
    constexpr int WSTR = MI + 8;
    constexpr int NT   = MO / 16;
    constexpr int KB   = MI / 32;
    constexpr int MTL  = 2 * D;
    constexpr int WCH  = (MO * WSTR) / 8;    // 16B chunks
    constexpr int XCH  = (RTILE * XP) / 8;

    const uint4* __restrict__ wsrc = (const uint4*)(wt_e + WB);
    const uint4* __restrict__ xsrc = (const uint4*)(xs_seg + (size_t)rbase * XP);
    for (int idx = t; idx < WCH; idx += 256) ((uint4*)lds_w)[idx] = wsrc[idx];
    for (int idx = t; idx < XCH; idx += 256) ((uint4*)lds_x)[idx] = xsrc[idx];
    __syncthreads();

    const int lane = t & 63, w = t >> 6;
    const int row_l = lane & 15, kg = lane >> 4;
    for (int ct = w; ct < MTL * NT; ct += 4) {
        const int mIdx = ct / NT, nt = ct - mIdx * NT;
        const int mt = mIdx & 1, mch = mIdx >> 1;
        f32x4 acc = {0.f, 0.f, 0.f, 0.f};
        #pragma unroll
        for (int kb = 0; kb < KB; ++kb) {
            const short8 a = *(const short8*)&lds_x[(mt * 16 + row_l) * XP + mch * MI + kb * 32 + kg * 8];
            const short8 b = *(const short8*)&lds_w[(nt * 16 + row_l) * WSTR + kb * 32 + kg * 8];
            acc = __builtin_amdgcn_mfma_f32_16x16x32_bf16(a, b, acc, 0, 0, 0);
        }
        const int o = nt * 16 + row_l;
        #pragma unroll
        for (int jj = 0; jj < 4; ++jj) {
            const int m = mt * 16 + kg * 4 + jj;
            if (m < nrows)
                out[(size_t)rid_s[m] * OUT_SIZE + YOFF + o * D + mch] = acc[jj];
        }
    }
}

__global__ __launch_bounds__(256) void gemm_kernel(
    const unsigned short* __restrict__ xs0, const unsigned short* __restrict__ xs1,
    const unsigned short* __restrict__ xs2, const unsigned short* __restrict__ wt,
    const int* __restrict__ rowids, const int* __restrict__ offsets,
    const int* __restrict__ tileoff, const int* __restrict__ blk2e,
    float* __restrict__ out) {
    // union LDS: seg0 96*104 + 32*104 = 13312 halves (26.6 KB) is the max
    __shared__ __align__(16) unsigned short lds[13312];
    __shared__ int rid_s[RTILE];

    const int t   = threadIdx.x;
    const int seg = blockIdx.x / MAXTILES;
    const int tb  = blockIdx.x - seg * MAXTILES;
    const int e   = blk2e[tb];
    if (e < 0) return;
    const int tile  = tb - tileoff[e];
    const int r0    = offsets[e];
    const int cnt   = offsets[e + 1] - r0;
    const int rbase = r0 + tile * RTILE;
    const int nrows = min(RTILE, cnt - tile * RTILE);
    if (t < nrows) rid_s[t] = rowids[rbase + t];
    __syncthreads();

    const unsigned short* wt_e = wt + (size_t)e * WT_ELEM;
    if (seg == 0)
        do_seg<96, 96, 1,   0,     0>(xs0, wt_e, rbase, rid_s, nrows, out, lds, lds + 9984, t);
    else if (seg == 1)
        do_seg<64, 64, 3,  96,  9984>(xs1, wt_e, rbase, rid_s, nrows, out, lds, lds + 4608, t);
    else
        do_seg<32, 32, 5, 288, 14592>(xs2, wt_e, rbase, rid_s, nrows, out, lds, lds + 1280, t);
}

// ---------------- launcher ----------------

extern "C" void kernel_launch(void* const* d_in, const int* in_sizes, int n_in,
                              void* d_out, int out_size, void* d_ws, size_t ws_size,
                              hipStream_t stream) {
    const float* weights = (const float*)d_in[0];   // [64, 14336] f32
    const float* x       = (const float*)d_in[1];   // [16384, 448] f32
    const int*   widx    = (const int*)d_in[2];     // [16384] int32
    float*       out     = (float*)d_out;           // [16384, 448] f32

    char* ws = (char*)d_ws;
    int* hists   = (int*)(ws + 0);                  // 128*64 ints = 32 KB
    int* offsets = (int*)(ws + 32768);              // 65
    int* tileoff = (int*)(ws + 33280);              // 65
    int* blk2e   = (int*)(ws + 33792);              // 576
    int* rowids  = (int*)(ws + 36864);              // 16384 ints
    unsigned short* wt  = (unsigned short*)(ws + 102400);    // 64*15872 halves = 1.94 MB
    unsigned short* xs0 = (unsigned short*)(ws + 2134016);   // 16416*104 halves
    unsigned short* xs1 = (unsigned short*)(ws + 5548544);   // 16416*200 halves
    unsigned short* xs2 = (unsigned short*)(ws + 12114944);  // 16416*168 halves

    hist_kernel    <<<128, 128, 0, stream>>>(widx, hists);
    scatterx_kernel<<<192, 1024, 0, stream>>>(widx, x, weights, hists,
                                              offsets, tileoff, blk2e, rowids,
                                              wt, xs0, xs1, xs2);
    gemm_kernel    <<<3 * MAXTILES, 256, 0, stream>>>(xs0, xs1, xs2, wt,
                                                      rowids, offsets, tileoff, blk2e, out);
}

// Round 6
// 50.592 us; speedup vs baseline: 1.5673x; 1.1818x over previous
//
#include <hip/hip_runtime.h>

// Indexed segmented linear, bucketed-by-element grouped GEMM with bf16 MFMA.
//   segments (mi, mo, d): (96,96,1), (64,64,3), (32,32,5)
//   y[b, o*d+m] = sum_i x[b, i*d+m] * W[idx[b], i*mo+o]
//
// Pipeline (4 kernels, no memset):
//   K1 hist    (128x128): per-128-row-chunk histogram of widx
//   K2 scatter (128x128): fused scan (per-block bases from hists) -> rowids;
//                         block 0 writes offsets/tileoff/blk2e tables
//   K3 combo   (576x256): blk 0-511  -> xprep: gather x[rowids[pos]] rows
//                         (coalesced reads), bf16-convert into per-wave LDS
//                         row buffer, write de-interleaved xs0/xs1/xs2
//                         POS-LINEAR (fully coalesced stores).
//                         blk 512-575 -> wprep: W -> bf16 transposed
//                         Wt[e][seg][o][i] (padded rows) via LDS transpose.
//   K4 gemm  (3*576x256): one block = (segment, 32-row tile); stage W seg +
//                         x tile as pure linear uint4 copies, 16x16x32 bf16
//                         MFMA, store f32 via rowids. (Unchanged R5 core.)

#define BATCH     16384
#define IN_SIZE   448
#define OUT_SIZE  448
#define W_SIZE    14336
#define NELEM     64
#define RTILE     32
#define MAXTILES  576         // >= 512 + 63 worst case
#define WT_ELEM   15872       // halves: 96*104 + 64*72 + 32*40

#define XP0 104               // xs row strides in halves (MI*D + 8)
#define XP1 200
#define XP2 168

typedef __attribute__((ext_vector_type(8))) short short8;
typedef __attribute__((ext_vector_type(4))) float f32x4;

__device__ __forceinline__ unsigned short f2bf(float f) {
    unsigned int u = __float_as_uint(f);
    u += 0x7fffu + ((u >> 16) & 1u);        // round-to-nearest-even
    return (unsigned short)(u >> 16);
}

// ---------------- K1: per-chunk histogram ----------------

__global__ __launch_bounds__(128) void hist_kernel(const int* __restrict__ widx,
                                                   int* __restrict__ hists) {
    __shared__ int h[NELEM];
    const int t = threadIdx.x;
    if (t < NELEM) h[t] = 0;
    __syncthreads();
    atomicAdd(&h[widx[blockIdx.x * 128 + t]], 1);
    __syncthreads();
    if (t < NELEM) hists[blockIdx.x * NELEM + t] = h[t];
}

// ---------------- K2: fused scan + scatter (rowids only) ----------------

__global__ __launch_bounds__(128) void scatter_kernel(
    const int* __restrict__ widx, const int* __restrict__ hists,
    int* __restrict__ offsets, int* __restrict__ tileoff, int* __restrict__ blk2e,
    int* __restrict__ rowids) {
    __shared__ int tot_s[NELEM], pre_s[NELEM], base_s[NELEM];
    __shared__ int off_s[NELEM + 1], tl_s[NELEM + 1];
    const int b = blockIdx.x, t = threadIdx.x;

    if (t < NELEM) {
        int before = 0, tot = 0;
        for (int c = 0; c < 128; ++c) {
            const int h = hists[c * NELEM + t];
            before += (c < b) ? h : 0;
            tot += h;
        }
        tot_s[t] = tot; pre_s[t] = before;
    }
    __syncthreads();
    if (t == 0) {
        int o = 0, tl = 0;
        for (int e = 0; e < NELEM; ++e) {
            off_s[e] = o; tl_s[e] = tl;
            o += tot_s[e]; tl += (tot_s[e] + RTILE - 1) >> 5;
        }
        off_s[NELEM] = o; tl_s[NELEM] = tl;
    }
    __syncthreads();
    if (t < NELEM) base_s[t] = off_s[t] + pre_s[t];

    if (b == 0) {
        if (t < NELEM) { offsets[t] = off_s[t]; tileoff[t] = tl_s[t]; }
        if (t == 0)    { offsets[NELEM] = off_s[NELEM]; tileoff[NELEM] = tl_s[NELEM]; }
        for (int i = t; i < MAXTILES; i += 128) blk2e[i] = -1;
        __syncthreads();
        if (t < NELEM)
            for (int bb = tl_s[t]; bb < tl_s[t + 1]; ++bb) blk2e[bb] = t;
    }
    __syncthreads();

    const int row = b * 128 + t;
    const int e = widx[row];
    const int pos = atomicAdd(&base_s[e], 1);
    rowids[pos] = row;
}

// ---------------- K3: xprep (pos-linear de-interleave) + wprep ----------------

__device__ __forceinline__ void wprep_seg(const float* __restrict__ we,
                                          unsigned short* __restrict__ de,
                                          unsigned short* lw, int t,
                                          int SRC, int CNT, int MO, int STR,
                                          int DB, int LWS, int MI) {
    for (int g = t; g < CNT; g += 256) {
        const int i = g / MO, o = g - i * MO;
        lw[i * LWS + o] = f2bf(we[SRC + g]);
    }
    __syncthreads();
    const int TOT = MO * STR;
    for (int d = t; d < TOT; d += 256) {
        const int o = d / STR, i = d - o * STR;
        de[DB + d] = (i < MI) ? lw[i * LWS + o] : (unsigned short)0;
    }
    __syncthreads();
}

__global__ __launch_bounds__(256) void combo_kernel(
    const float* __restrict__ x, const float* __restrict__ weights,
    const int* __restrict__ rowids, unsigned short* __restrict__ wt,
    unsigned short* __restrict__ xs0, unsigned short* __restrict__ xs1,
    unsigned short* __restrict__ xs2) {
    __shared__ __align__(16) unsigned short lw[9408];   // wprep: 96*98; xprep: 4*456
    const int t = threadIdx.x;

    if (blockIdx.x >= 512) {                 // ---- wprep role ----
        const int e = blockIdx.x - 512;
        const float* __restrict__ we = weights + e * W_SIZE;
        unsigned short* __restrict__ de = wt + (size_t)e * WT_ELEM;
        wprep_seg(we, de, lw, t,     0, 9216, 96, 104,     0, 98, 96);
        wprep_seg(we, de, lw, t,  9216, 4096, 64,  72,  9984, 66, 64);
        wprep_seg(we, de, lw, t, 13312, 1024, 32,  40, 14592, 34, 32);
        return;
    }

    // ---- xprep role: 4 waves/block, 8 consecutive pos per wave ----
    const int wv = t >> 6, l = t & 63;
    unsigned short* xb = lw + wv * 456;      // per-wave row buffer (448 + pad)
    const int pos0 = (blockIdx.x * 4 + wv) * 8;

    for (int r = 0; r < 8; ++r) {
        const int pos = pos0 + r;
        const int row = rowids[pos];
        const float* __restrict__ xr = x + (size_t)row * IN_SIZE;
        #pragma unroll
        for (int k = 0; k < 7; ++k)
            xb[k * 64 + l] = f2bf(xr[k * 64 + l]);   // coalesced 256B reads
        __syncthreads();

        // xs0: out p = c (seg0 source c = p)
        {
            unsigned short* __restrict__ d0 = xs0 + (size_t)pos * XP0;
            d0[l] = (l < 96) ? xb[l] : (unsigned short)0;
            if (l < 32) d0[64 + l] = (64 + l < 96) ? xb[64 + l] : (unsigned short)0;
        }
        // xs1: out p = m*64 + i -> src 96 + i*3 + m ; p = it*64 + l => m=it, i=l
        {
            unsigned short* __restrict__ d1 = xs1 + (size_t)pos * XP1;
            #pragma unroll
            for (int it = 0; it < 3; ++it)
                d1[it * 64 + l] = xb[96 + l * 3 + it];
        }
        // xs2: out p = m*32 + i -> src 288 + i*5 + m ; m = p>>5, i = p&31
        {
            unsigned short* __restrict__ d2 = xs2 + (size_t)pos * XP2;
            #pragma unroll
            for (int it = 0; it < 3; ++it) {
                const int p = it * 64 + l;
                if (p < 160) d2[p] = xb[288 + (p & 31) * 5 + (p >> 5)];
            }
        }
        __syncthreads();                     // before next row overwrites xb
    }
}

// ---------------- K4: grouped GEMM, one block = (segment, tile) ----------------

template <int MI, int MO, int D, int YOFF, int WB>
__device__ __forceinline__ void do_seg(const unsigned short* __restrict__ xs_seg,
                                       const unsigned short* __restrict__ wt_e,
                                       int rbase, const int* rid_s, int nrows,
                                       float* __restrict__ out,
                                       unsigned short* lds_w, unsigned short* lds_x,
                                       int t) {
    constexpr int XP   = MI * D + 8;
    constexpr int WSTR = MI + 8;
    constexpr int NT   = MO / 16;
    constexpr int KB   = MI / 32;
    constexpr int MTL  = 2 * D;
    constexpr int WCH  = (MO * WSTR) / 8;    // 16B chunks
    constexpr int XCH  = (RTILE * XP) / 8;

    const uint4* __restrict__ wsrc = (const uint4*)(wt_e + WB);
    const uint4* __restrict__ xsrc = (const uint4*)(xs_seg + (size_t)rbase * XP);
    for (int idx = t; idx < WCH; idx += 256) ((uint4*)lds_w)[idx] = wsrc[idx];
    for (int idx = t; idx < XCH; idx += 256) ((uint4*)lds_x)[idx] = xsrc[idx];
    __syncthreads();

    const int lane = t & 63, w = t >> 6;
    const int row_l = lane & 15, kg = lane >> 4;
    for (int ct = w; ct < MTL * NT; ct += 4) {
        const int mIdx = ct / NT, nt = ct - mIdx * NT;
        const int mt = mIdx & 1, mch = mIdx >> 1;
        f32x4 acc = {0.f, 0.f, 0.f, 0.f};
        #pragma unroll
        for (int kb = 0; kb < KB; ++kb) {
            const short8 a = *(const short8*)&lds_x[(mt * 16 + row_l) * XP + mch * MI + kb * 32 + kg * 8];
            const short8 b = *(const short8*)&lds_w[(nt * 16 + row_l) * WSTR + kb * 32 + kg * 8];
            acc = __builtin_amdgcn_mfma_f32_16x16x32_bf16(a, b, acc, 0, 0, 0);
        }
        const int o = nt * 16 + row_l;
        #pragma unroll
        for (int jj = 0; jj < 4; ++jj) {
            const int m = mt * 16 + kg * 4 + jj;
            if (m < nrows)
                out[(size_t)rid_s[m] * OUT_SIZE + YOFF + o * D + mch] = acc[jj];
        }
    }
}

__global__ __launch_bounds__(256) void gemm_kernel(
    const unsigned short* __restrict__ xs0, const unsigned short* __restrict__ xs1,
    const unsigned short* __restrict__ xs2, const unsigned short* __restrict__ wt,
    const int* __restrict__ rowids, const int* __restrict__ offsets,
    const int* __restrict__ tileoff, const int* __restrict__ blk2e,
    float* __restrict__ out) {
    // union LDS: seg0 96*104 + 32*104 = 13312 halves (26.6 KB) is the max
    __shared__ __align__(16) unsigned short lds[13312];
    __shared__ int rid_s[RTILE];

    const int t   = threadIdx.x;
    const int seg = blockIdx.x / MAXTILES;
    const int tb  = blockIdx.x - seg * MAXTILES;
    const int e   = blk2e[tb];
    if (e < 0) return;
    const int tile  = tb - tileoff[e];
    const int r0    = offsets[e];
    const int cnt   = offsets[e + 1] - r0;
    const int rbase = r0 + tile * RTILE;
    const int nrows = min(RTILE, cnt - tile * RTILE);
    if (t < nrows) rid_s[t] = rowids[rbase + t];
    __syncthreads();

    const unsigned short* wt_e = wt + (size_t)e * WT_ELEM;
    if (seg == 0)
        do_seg<96, 96, 1,   0,     0>(xs0, wt_e, rbase, rid_s, nrows, out, lds, lds + 9984, t);
    else if (seg == 1)
        do_seg<64, 64, 3,  96,  9984>(xs1, wt_e, rbase, rid_s, nrows, out, lds, lds + 4608, t);
    else
        do_seg<32, 32, 5, 288, 14592>(xs2, wt_e, rbase, rid_s, nrows, out, lds, lds + 1280, t);
}

// ---------------- launcher ----------------

extern "C" void kernel_launch(void* const* d_in, const int* in_sizes, int n_in,
                              void* d_out, int out_size, void* d_ws, size_t ws_size,
                              hipStream_t stream) {
    const float* weights = (const float*)d_in[0];   // [64, 14336] f32
    const float* x       = (const float*)d_in[1];   // [16384, 448] f32
    const int*   widx    = (const int*)d_in[2];     // [16384] int32
    float*       out     = (float*)d_out;           // [16384, 448] f32

    char* ws = (char*)d_ws;
    int* hists   = (int*)(ws + 0);                  // 128*64 ints = 32 KB
    int* offsets = (int*)(ws + 32768);              // 65
    int* tileoff = (int*)(ws + 33280);              // 65
    int* blk2e   = (int*)(ws + 33792);              // 576
    int* rowids  = (int*)(ws + 36864);              // 16384 ints
    unsigned short* wt  = (unsigned short*)(ws + 102400);    // 64*15872 halves = 1.94 MB
    unsigned short* xs0 = (unsigned short*)(ws + 2134016);   // 16416*104 halves
    unsigned short* xs1 = (unsigned short*)(ws + 5548544);   // 16416*200 halves
    unsigned short* xs2 = (unsigned short*)(ws + 12114944);  // 16416*168 halves

    hist_kernel   <<<128, 128, 0, stream>>>(widx, hists);
    scatter_kernel<<<128, 128, 0, stream>>>(widx, hists, offsets, tileoff, blk2e, rowids);
    combo_kernel  <<<576, 256, 0, stream>>>(x, weights, rowids, wt, xs0, xs1, xs2);
    gemm_kernel   <<<3 * MAXTILES, 256, 0, stream>>>(xs0, xs1, xs2, wt,
                                                     rowids, offsets, tileoff, blk2e, out);
}

// Round 7
// 41.388 us; speedup vs baseline: 1.9158x; 1.2224x over previous
//
#include <hip/hip_runtime.h>

// Indexed segmented linear, bucketed-by-element grouped GEMM with bf16 MFMA.
//   segments (mi, mo, d): (96,96,1), (64,64,3), (32,32,5)
//   y[b, o*d+m] = sum_i x[b, i*d+m] * W[idx[b], i*mo+o]
//
// Pipeline (3 kernels, no memset):
//   K1 combo1 (128x256): blk 0-63  -> per-256-row-chunk histogram of widx
//                        blk 64-127-> wprep: W -> bf16 transposed
//                                     Wt[e][seg][o][i] (padded) via LDS
//   K2 scatter (64x256): fused scan (per-block bases from hists) -> rowids;
//                        block 0 writes offsets/tileoff/blk2e tables
//   K3 gemm (3*576x256): one block = (segment, 32-row tile). Stage W seg
//                        (linear uint4) + GATHER x slice rows via rid_s,
//                        de-interleave+bf16-convert during the LDS write
//                        (segments read disjoint x slices -> x read once
//                        total). 16x16x32 bf16 MFMA, store f32 via rid_s.

#define BATCH     16384
#define IN_SIZE   448
#define OUT_SIZE  448
#define W_SIZE    14336
#define NELEM     64
#define RTILE     32
#define MAXTILES  576         // >= 512 + 63 worst case
#define WT_ELEM   15872       // halves: 96*104 + 64*72 + 32*40

typedef __attribute__((ext_vector_type(8))) short short8;
typedef __attribute__((ext_vector_type(4))) float f32x4;

__device__ __forceinline__ unsigned short f2bf(float f) {
    unsigned int u = __float_as_uint(f);
    u += 0x7fffu + ((u >> 16) & 1u);        // round-to-nearest-even
    return (unsigned short)(u >> 16);
}

// ---------------- K1: hist (blk 0-63) + wprep (blk 64-127) ----------------

__device__ __forceinline__ void wprep_seg(const float* __restrict__ we,
                                          unsigned short* __restrict__ de,
                                          unsigned short* lw, int t,
                                          int SRC, int CNT, int MO, int STR,
                                          int DB, int LWS, int MI) {
    for (int g = t; g < CNT; g += 256) {
        const int i = g / MO, o = g - i * MO;
        lw[i * LWS + o] = f2bf(we[SRC + g]);
    }
    __syncthreads();
    const int TOT = MO * STR;
    for (int d = t; d < TOT; d += 256) {
        const int o = d / STR, i = d - o * STR;
        de[DB + d] = (i < MI) ? lw[i * LWS + o] : (unsigned short)0;
    }
    __syncthreads();
}

__global__ __launch_bounds__(256) void combo1_kernel(
    const int* __restrict__ widx, const float* __restrict__ weights,
    int* __restrict__ hists, unsigned short* __restrict__ wt) {
    __shared__ int h[NELEM];
    __shared__ __align__(16) unsigned short lw[9408];   // 96*98 padded
    const int t = threadIdx.x;
    if (blockIdx.x < 64) {
        if (t < NELEM) h[t] = 0;
        __syncthreads();
        atomicAdd(&h[widx[blockIdx.x * 256 + t]], 1);
        __syncthreads();
        if (t < NELEM) hists[blockIdx.x * NELEM + t] = h[t];
    } else {
        const int e = blockIdx.x - 64;
        const float* __restrict__ we = weights + e * W_SIZE;
        unsigned short* __restrict__ de = wt + (size_t)e * WT_ELEM;
        wprep_seg(we, de, lw, t,     0, 9216, 96, 104,     0, 98, 96);
        wprep_seg(we, de, lw, t,  9216, 4096, 64,  72,  9984, 66, 64);
        wprep_seg(we, de, lw, t, 13312, 1024, 32,  40, 14592, 34, 32);
    }
}

// ---------------- K2: fused scan + scatter (rowids + tables) ----------------

__global__ __launch_bounds__(256) void scatter_kernel(
    const int* __restrict__ widx, const int* __restrict__ hists,
    int* __restrict__ offsets, int* __restrict__ tileoff, int* __restrict__ blk2e,
    int* __restrict__ rowids) {
    __shared__ int tot_s[NELEM], pre_s[NELEM], base_s[NELEM];
    __shared__ int off_s[NELEM + 1], tl_s[NELEM + 1];
    const int b = blockIdx.x, t = threadIdx.x;

    if (t < NELEM) {
        int before = 0, tot = 0;
        for (int c = 0; c < 64; ++c) {
            const int h = hists[c * NELEM + t];
            before += (c < b) ? h : 0;
            tot += h;
        }
        tot_s[t] = tot; pre_s[t] = before;
    }
    __syncthreads();
    if (t == 0) {
        int o = 0, tl = 0;
        for (int e = 0; e < NELEM; ++e) {
            off_s[e] = o; tl_s[e] = tl;
            o += tot_s[e]; tl += (tot_s[e] + RTILE - 1) >> 5;
        }
        off_s[NELEM] = o; tl_s[NELEM] = tl;
    }
    __syncthreads();
    if (t < NELEM) base_s[t] = off_s[t] + pre_s[t];

    if (b == 0) {
        if (t < NELEM) { offsets[t] = off_s[t]; tileoff[t] = tl_s[t]; }
        if (t == 0)    { offsets[NELEM] = off_s[NELEM]; tileoff[NELEM] = tl_s[NELEM]; }
        for (int i = t; i < MAXTILES; i += 256) blk2e[i] = -1;
        __syncthreads();
        if (t < NELEM)
            for (int bb = tl_s[t]; bb < tl_s[t + 1]; ++bb) blk2e[bb] = t;
    }
    __syncthreads();

    const int row = b * 256 + t;
    const int e = widx[row];
    const int pos = atomicAdd(&base_s[e], 1);
    rowids[pos] = row;
}

// ---------------- K3: grouped GEMM with fused gather + de-interleave ----------

template <int MI, int MO, int D, int XOFF, int YOFF, int WB>
__device__ __forceinline__ void do_seg(const float* __restrict__ x,
                                       const unsigned short* __restrict__ wt_e,
                                       const int* rid_s, int nrows,
                                       float* __restrict__ out,
                                       unsigned short* lds_w, unsigned short* lds_x,
                                       int t) {
    constexpr int XP   = MI * D + 8;         // x row stride (halves)
    constexpr int WSTR = MI + 8;             // W row stride (halves)
    constexpr int NT   = MO / 16;
    constexpr int KB   = MI / 32;
    constexpr int MTL  = 2 * D;
    constexpr int WCH  = (MO * WSTR) / 8;    // 16B chunks
    constexpr int FPT  = (MI * D) / 8;       // floats per thread (8 thr/row)

    // stage W segment (bf16, pre-transposed, padded): linear uint4 copies
    const uint4* __restrict__ wsrc = (const uint4*)(wt_e + WB);
    for (int idx = t; idx < WCH; idx += 256) ((uint4*)lds_w)[idx] = wsrc[idx];

    // gather x slice rows + de-interleave (i*D+m -> [m][i]) + bf16 convert
    {
        const int r = t >> 3, j = t & 7;     // 8 threads per row
        const float* __restrict__ xr = x + (size_t)rid_s[r] * IN_SIZE + XOFF + j * FPT;
        #pragma unroll
        for (int q = 0; q < FPT / 4; ++q) {
            const float4 v = ((const float4*)xr)[q];
            const float vv[4] = { v.x, v.y, v.z, v.w };
            #pragma unroll
            for (int u = 0; u < 4; ++u) {
                const int c = j * FPT + q * 4 + u;     // slice-local source idx
                const unsigned short bf = f2bf(vv[u]);
                if (D == 1) {
                    lds_x[r * XP + c] = bf;
                } else {
                    const int i = c / D, m = c - i * D;
                    lds_x[r * XP + m * MI + i] = bf;
                }
            }
        }
    }
    __syncthreads();

    // compute: C-tiles round-robin over 4 waves
    const int lane = t & 63, w = t >> 6;
    const int row_l = lane & 15, kg = lane >> 4;
    for (int ct = w; ct < MTL * NT; ct += 4) {
        const int mIdx = ct / NT, nt = ct - mIdx * NT;
        const int mt = mIdx & 1, mch = mIdx >> 1;
        f32x4 acc = {0.f, 0.f, 0.f, 0.f};
        #pragma unroll
        for (int kb = 0; kb < KB; ++kb) {
            const short8 a = *(const short8*)&lds_x[(mt * 16 + row_l) * XP + mch * MI + kb * 32 + kg * 8];
            const short8 b = *(const short8*)&lds_w[(nt * 16 + row_l) * WSTR + kb * 32 + kg * 8];
            acc = __builtin_amdgcn_mfma_f32_16x16x32_bf16(a, b, acc, 0, 0, 0);
        }
        const int o = nt * 16 + row_l;
        #pragma unroll
        for (int jj = 0; jj < 4; ++jj) {
            const int m = mt * 16 + kg * 4 + jj;
            if (m < nrows)
                out[(size_t)rid_s[m] * OUT_SIZE + YOFF + o * D + mch] = acc[jj];
        }
    }
}

__global__ __launch_bounds__(256) void gemm_kernel(
    const float* __restrict__ x, const unsigned short* __restrict__ wt,
    const int* __restrict__ rowids, const int* __restrict__ offsets,
    const int* __restrict__ tileoff, const int* __restrict__ blk2e,
    float* __restrict__ out) {
    // union LDS: seg0 96*104 + 32*104 = 13312 halves (26.6 KB) is the max
    __shared__ __align__(16) unsigned short lds[13312];
    __shared__ int rid_s[RTILE];

    const int t   = threadIdx.x;
    const int seg = blockIdx.x / MAXTILES;
    const int tb  = blockIdx.x - seg * MAXTILES;
    const int e   = blk2e[tb];
    if (e < 0) return;
    const int tile  = tb - tileoff[e];
    const int r0    = offsets[e];
    const int cnt   = offsets[e + 1] - r0;
    const int rbase = r0 + tile * RTILE;
    const int nrows = min(RTILE, cnt - tile * RTILE);
    if (t < RTILE) rid_s[t] = rowids[rbase + min(t, nrows - 1)];  // clamp: ghosts gather real rows
    __syncthreads();

    const unsigned short* wt_e = wt + (size_t)e * WT_ELEM;
    if (seg == 0)
        do_seg<96, 96, 1,   0,   0,     0>(x, wt_e, rid_s, nrows, out, lds, lds + 9984, t);
    else if (seg == 1)
        do_seg<64, 64, 3,  96,  96,  9984>(x, wt_e, rid_s, nrows, out, lds, lds + 4608, t);
    else
        do_seg<32, 32, 5, 288, 288, 14592>(x, wt_e, rid_s, nrows, out, lds, lds + 1280, t);
}

// ---------------- launcher ----------------

extern "C" void kernel_launch(void* const* d_in, const int* in_sizes, int n_in,
                              void* d_out, int out_size, void* d_ws, size_t ws_size,
                              hipStream_t stream) {
    const float* weights = (const float*)d_in[0];   // [64, 14336] f32
    const float* x       = (const float*)d_in[1];   // [16384, 448] f32
    const int*   widx    = (const int*)d_in[2];     // [16384] int32
    float*       out     = (float*)d_out;           // [16384, 448] f32

    char* ws = (char*)d_ws;
    int* hists   = (int*)(ws + 0);                  // 64*64 ints = 16 KB
    int* offsets = (int*)(ws + 16384);              // 65
    int* tileoff = (int*)(ws + 16896);              // 65
    int* blk2e   = (int*)(ws + 17408);              // 576
    int* rowids  = (int*)(ws + 20480);              // 16384 ints
    unsigned short* wt = (unsigned short*)(ws + 86016);   // 64*15872 halves = 1.94 MB

    combo1_kernel <<<128, 256, 0, stream>>>(widx, weights, hists, wt);
    scatter_kernel<<<64,  256, 0, stream>>>(widx, hists, offsets, tileoff, blk2e, rowids);
    gemm_kernel   <<<3 * MAXTILES, 256, 0, stream>>>(x, wt, rowids, offsets, tileoff, blk2e, out);
}